// Round 4
// baseline (276.524 us; speedup 1.0000x reference)
//
#include <hip/hip_runtime.h>
#include <math.h>

#define BATCH 32
#define DIM   4096
#define CLEN  4096
#define HD    128
#define NKV   8
#define NHEAD 32
#define QKVN  6144          // (32 + 2*8) * 128
#define KVSTR (NKV * HD)    // 1024 floats between consecutive t rows
#define GN    64            // N per gemm block
#define KSEG  128           // K per gemm stage
#define KSTG  4             // stages per block
#define KTOT  512           // KSEG*KSTG
#define NSEG  8             // 4096 / 512
#define NCHB  16            // chunks per b (one block each)
#define TC    256           // rows per block-chunk
#define NSLOT 16            // one slot per chunk
#define MNEG  -1.0e30f
#define SMASK -3.0e38f

// ---------------- helpers ----------------
template <int CTRL>
__device__ __forceinline__ float dpp_add(float x) {
  int y = __builtin_amdgcn_update_dpp(0, __float_as_int(x), CTRL, 0xF, 0xF, true);
  return x + __int_as_float(y);
}

// sum across the 32 lanes of each half-wave
__device__ __forceinline__ float half_reduce(float s) {
  s = dpp_add<0xB1>(s);    // quad_perm xor1
  s = dpp_add<0x4E>(s);    // quad_perm xor2
  s = dpp_add<0x124>(s);   // row_ror:4
  s = dpp_add<0x128>(s);   // row_ror:8
  s += __int_as_float(__builtin_amdgcn_ds_swizzle(__float_as_int(s), 0x401F)); // xor16
  return s;
}

// ---------------- skinny GEMM partial: part[seg][b][n] = sum_{k in seg} X[b][k]*W[n][k]
// LDS layouts: xs[k][32] / wl[k][64], quad-XOR swizzled: physquad = quad ^ ((k>>2)&7)
__global__ __launch_bounds__(256)
void gemm_partial(const float* __restrict__ X, const float* __restrict__ W,
                  float* __restrict__ part, const int N) {
  __shared__ float xs[KSEG * 32];
  __shared__ float wl[KSEG * 64];
  const int tid = threadIdx.x;
  const int c   = tid & 31;        // k-quad index
  const int r   = tid >> 5;        // 0..7
  const int cx7 = c & 7;
  const int n0  = blockIdx.x * GN;
  const int k00 = blockIdx.y * KTOT;
  const int bq8 = tid & 7;         // b-quad for compute
  const int tq  = tid >> 3;        // 0..31
  const int nqq = tq >> 1;         // n-quad 0..15
  const int nqo = (tq & 1) << 1;   // 0 or 2

  float a00=0,a01=0, a10=0,a11=0, a20=0,a21=0, a30=0,a31=0;

  float* xwp  = xs + (c * 4) * 32 + ((r ^ cx7) << 2);
  float* wwp0 = wl + (c * 4) * 64 + ((r ^ cx7) << 2);
  float* wwp1 = wwp0 + 32;         // physquad p=1 -> +8 quads

  // ---- preload stage 0 ----
  float4 xv0, xv1, xv2, xv3, wv00, wv01, wv02, wv03, wv10, wv11, wv12, wv13;
  {
    const float* Xp = X + (size_t)(r * 4) * DIM + k00 + c * 4;
    xv0 = *(const float4*)(Xp);
    xv1 = *(const float4*)(Xp + DIM);
    xv2 = *(const float4*)(Xp + 2 * DIM);
    xv3 = *(const float4*)(Xp + 3 * DIM);
    const float* Wp0 = W + (size_t)(n0 + r * 4) * DIM + k00 + c * 4;
    wv00 = *(const float4*)(Wp0);
    wv01 = *(const float4*)(Wp0 + DIM);
    wv02 = *(const float4*)(Wp0 + 2 * DIM);
    wv03 = *(const float4*)(Wp0 + 3 * DIM);
    const float* Wp1 = Wp0 + (size_t)32 * DIM;
    wv10 = *(const float4*)(Wp1);
    wv11 = *(const float4*)(Wp1 + DIM);
    wv12 = *(const float4*)(Wp1 + 2 * DIM);
    wv13 = *(const float4*)(Wp1 + 3 * DIM);
  }

  for (int kk = 0; kk < KSTG; ++kk) {
    if (kk) __syncthreads();       // previous compute done before LDS overwrite

    // ---- register 4x4 transpose -> b128 LDS writes (4-way max) ----
    *(float4*)(xwp + 0)   = make_float4(xv0.x, xv1.x, xv2.x, xv3.x);
    *(float4*)(xwp + 32)  = make_float4(xv0.y, xv1.y, xv2.y, xv3.y);
    *(float4*)(xwp + 64)  = make_float4(xv0.z, xv1.z, xv2.z, xv3.z);
    *(float4*)(xwp + 96)  = make_float4(xv0.w, xv1.w, xv2.w, xv3.w);
    *(float4*)(wwp0 + 0)   = make_float4(wv00.x, wv01.x, wv02.x, wv03.x);
    *(float4*)(wwp0 + 64)  = make_float4(wv00.y, wv01.y, wv02.y, wv03.y);
    *(float4*)(wwp0 + 128) = make_float4(wv00.z, wv01.z, wv02.z, wv03.z);
    *(float4*)(wwp0 + 192) = make_float4(wv00.w, wv01.w, wv02.w, wv03.w);
    *(float4*)(wwp1 + 0)   = make_float4(wv10.x, wv11.x, wv12.x, wv13.x);
    *(float4*)(wwp1 + 64)  = make_float4(wv10.y, wv11.y, wv12.y, wv13.y);
    *(float4*)(wwp1 + 128) = make_float4(wv10.z, wv11.z, wv12.z, wv13.z);
    *(float4*)(wwp1 + 192) = make_float4(wv10.w, wv11.w, wv12.w, wv13.w);
    __syncthreads();

    // ---- issue next-stage global loads (latency hides under compute) ----
    if (kk + 1 < KSTG) {
      const int k0 = k00 + (kk + 1) * KSEG;
      const float* Xp = X + (size_t)(r * 4) * DIM + k0 + c * 4;
      xv0 = *(const float4*)(Xp);
      xv1 = *(const float4*)(Xp + DIM);
      xv2 = *(const float4*)(Xp + 2 * DIM);
      xv3 = *(const float4*)(Xp + 3 * DIM);
      const float* Wp0 = W + (size_t)(n0 + r * 4) * DIM + k0 + c * 4;
      wv00 = *(const float4*)(Wp0);
      wv01 = *(const float4*)(Wp0 + DIM);
      wv02 = *(const float4*)(Wp0 + 2 * DIM);
      wv03 = *(const float4*)(Wp0 + 3 * DIM);
      const float* Wp1 = Wp0 + (size_t)32 * DIM;
      wv10 = *(const float4*)(Wp1);
      wv11 = *(const float4*)(Wp1 + DIM);
      wv12 = *(const float4*)(Wp1 + 2 * DIM);
      wv13 = *(const float4*)(Wp1 + 3 * DIM);
    }

    // ---- compute: g = (k>>2)&7 constant per unrolled body ----
#pragma unroll 8
    for (int k2 = 0; k2 < KSEG / 4; ++k2) {
      const int g = k2 & 7;
      const float* xr = xs + (k2 * 4) * 32 + ((bq8 ^ g) << 2);
      const float* wr = wl + (k2 * 4) * 64 + ((nqq ^ g) << 2) + nqo;
#pragma unroll
      for (int j = 0; j < 4; ++j) {
        const float4 xv = *(const float4*)(xr + j * 32);
        const float2 wv = *(const float2*)(wr + j * 64);
        a00 = fmaf(xv.x, wv.x, a00); a01 = fmaf(xv.x, wv.y, a01);
        a10 = fmaf(xv.y, wv.x, a10); a11 = fmaf(xv.y, wv.y, a11);
        a20 = fmaf(xv.z, wv.x, a20); a21 = fmaf(xv.z, wv.y, a21);
        a30 = fmaf(xv.w, wv.x, a30); a31 = fmaf(xv.w, wv.y, a31);
      }
    }
  }
  const int bq = bq8 << 2;
  const int nq = tq << 1;
  float* base = part + ((size_t)blockIdx.y * BATCH + bq) * N + n0 + nq;
  *(float2*)(base)         = make_float2(a00, a01);
  *(float2*)(base + N)     = make_float2(a10, a11);
  *(float2*)(base + 2 * N) = make_float2(a20, a21);
  *(float2*)(base + 3 * N) = make_float2(a30, a31);
}

// ---------------- qkv combine + RoPE ----------------
__global__ __launch_bounds__(256)
void qkv_combine(const float* __restrict__ part, const int* __restrict__ ctxp,
                 float* __restrict__ qw, float* __restrict__ kn, float* __restrict__ vn) {
  const int idx = blockIdx.x * 256 + threadIdx.x;  // pair index: 32*3072
  const int b  = idx / (QKVN / 2);
  const int c  = idx % (QKVN / 2);
  const int n0 = c * 2;
  float v0 = 0.f, v1 = 0.f;
#pragma unroll
  for (int s = 0; s < NSEG; ++s) {
    const float2 pv = *(const float2*)(part + ((size_t)s * BATCH + b) * QKVN + n0);
    v0 += pv.x; v1 += pv.y;
  }
  const float pos = (float)ctxp[0];
  const float L2T_OVER_64 = 0.20762050593045952f;  // log2(10000)/64
  if (n0 < DIM) {
    const int i = (n0 & 127) >> 1;
    const float fr = exp2f(-(float)i * L2T_OVER_64);
    float sn, cs; sincosf(pos * fr, &sn, &cs);
    qw[(size_t)b * DIM + n0]     = v0 * cs - v1 * sn;
    qw[(size_t)b * DIM + n0 + 1] = v0 * sn + v1 * cs;
  } else if (n0 < DIM + NKV * HD) {
    const int nk = n0 - DIM;
    const int i = (nk & 127) >> 1;
    const float fr = exp2f(-(float)i * L2T_OVER_64);
    float sn, cs; sincosf(pos * fr, &sn, &cs);
    kn[(size_t)b * (NKV * HD) + nk]     = v0 * cs - v1 * sn;
    kn[(size_t)b * (NKV * HD) + nk + 1] = v0 * sn + v1 * cs;
  } else {
    const int nv = n0 - DIM - NKV * HD;
    vn[(size_t)b * (NKV * HD) + nv]     = v0;
    vn[(size_t)b * (NKV * HD) + nv + 1] = v1;
  }
}

// ---------------- flash-decode: dense-row streaming, block owns (b, chunk) ----------------
// wave w, half h -> g = 2w + h; per row the wave reads a contiguous 1 KB slice,
// the block reads the full dense 4 KB row. No half-merge needed (halves = different g).
__device__ __forceinline__ void load4(float4 kb[4], float4 vb[4],
    const float* __restrict__ kbase, const float* __restrict__ vbase,
    const float* __restrict__ knr, const float* __restrict__ vnr,
    const int t0, const int ctx, const bool edge) {
#pragma unroll
  for (int u = 0; u < 4; ++u) {
    const int row = t0 + u;
    const float* kp = kbase + (size_t)row * KVSTR;
    const float* vp = vbase + (size_t)row * KVSTR;
    if (edge) {                       // wave-uniform branch
      if (row == ctx) { kp = knr; vp = vnr; }
    }
    kb[u] = *(const float4*)kp;
    vb[u] = *(const float4*)vp;
  }
}

__device__ __forceinline__ void compute4(const float4 kb[4], const float4 vb[4],
    const float4 q[4], const int t0, const int ctx, const bool edge,
    float m[4], float l[4], float4 acc[4]) {
#pragma unroll
  for (int u = 0; u < 4; ++u) {
    float s[4];
#pragma unroll
    for (int hh = 0; hh < 4; ++hh) {
      float d = fmaf(kb[u].x, q[hh].x, kb[u].y * q[hh].y);
      d = fmaf(kb[u].z, q[hh].z, d);
      d = fmaf(kb[u].w, q[hh].w, d);
      s[hh] = half_reduce(d);
    }
    if (edge) {                       // wave-uniform branch (row uniform across wave)
      if (t0 + u > ctx) { s[0] = SMASK; s[1] = SMASK; s[2] = SMASK; s[3] = SMASK; }
    }
    if ((s[0] > m[0]) | (s[1] > m[1]) | (s[2] > m[2]) | (s[3] > m[3])) {
#pragma unroll
      for (int hh = 0; hh < 4; ++hh) {
        const float mn = fmaxf(m[hh], s[hh]);
        const float rs = __expf(m[hh] - mn);
        l[hh] *= rs;
        acc[hh].x *= rs; acc[hh].y *= rs; acc[hh].z *= rs; acc[hh].w *= rs;
        m[hh] = mn;
      }
    }
#pragma unroll
    for (int hh = 0; hh < 4; ++hh) {
      const float p = __expf(s[hh] - m[hh]);
      l[hh] += p;
      acc[hh].x = fmaf(p, vb[u].x, acc[hh].x);
      acc[hh].y = fmaf(p, vb[u].y, acc[hh].y);
      acc[hh].z = fmaf(p, vb[u].z, acc[hh].z);
      acc[hh].w = fmaf(p, vb[u].w, acc[hh].w);
    }
  }
}

__global__ __launch_bounds__(256)
void attn_fd(const float* __restrict__ qw, const float* __restrict__ knew,
             const float* __restrict__ vnew, const float* __restrict__ ck,
             const float* __restrict__ cv, const int* __restrict__ ctxp,
             float* __restrict__ opart, float* __restrict__ mlp) {
  const int b    = blockIdx.x >> 4;
  const int cidx = blockIdx.x & (NCHB - 1);
  const int wid  = threadIdx.x >> 6;
  const int lane = threadIdx.x & 63;
  const int half = lane >> 5;
  const int g    = wid * 2 + half;
  const int d4   = (lane & 31) << 2;
  const int ctx  = ctxp[0];
  const int c0   = cidx * TC;

  const float sc = 0.08838834764831845f;   // 1/sqrt(128)
  float4 q[4];
#pragma unroll
  for (int hh = 0; hh < 4; ++hh) {
    q[hh] = *(const float4*)(qw + ((size_t)b * NHEAD + g * 4 + hh) * HD + d4);
    q[hh].x *= sc; q[hh].y *= sc; q[hh].z *= sc; q[hh].w *= sc;
  }
  const float* kbase = ck + ((size_t)b * CLEN) * KVSTR + g * HD + d4;
  const float* vbase = cv + ((size_t)b * CLEN) * KVSTR + g * HD + d4;
  const float* knr   = knew + ((size_t)b * NKV + g) * HD + d4;
  const float* vnr   = vnew + ((size_t)b * NKV + g) * HD + d4;

  float m[4] = {MNEG, MNEG, MNEG, MNEG};
  float l[4] = {0.f, 0.f, 0.f, 0.f};
  float4 acc[4] = {};

  float4 kA[4], vA[4], kB[4], vB[4];
  load4(kA, vA, kbase, vbase, knr, vnr, c0, ctx, c0 + 4 > ctx);
  for (int it = 0; it < TC / 8; ++it) {
    const int t0 = c0 + it * 8;
    load4(kB, vB, kbase, vbase, knr, vnr, t0 + 4, ctx, t0 + 8 > ctx);
    compute4(kA, vA, q, t0, ctx, t0 + 4 > ctx, m, l, acc);
    if (it + 1 < TC / 8)
      load4(kA, vA, kbase, vbase, knr, vnr, t0 + 8, ctx, t0 + 12 > ctx);
    compute4(kB, vB, q, t0 + 4, ctx, t0 + 8 > ctx, m, l, acc);
  }

#pragma unroll
  for (int hh = 0; hh < 4; ++hh) {
    const int hid = b * NHEAD + g * 4 + hh;
    const size_t slot = (size_t)hid * NSLOT + cidx;
    *(float4*)(opart + slot * HD + d4) = acc[hh];
    if ((lane & 31) == 0) { mlp[slot * 2] = m[hh]; mlp[slot * 2 + 1] = l[hh]; }
  }
}

// ---------------- flash combine ----------------
__global__ __launch_bounds__(128)
void attn_combine(const float* __restrict__ opart, const float* __restrict__ mlp,
                  float* __restrict__ ow) {
  const int p = blockIdx.x;      // 0..1023 = b*32 + g*4 + h
  const int d = threadIdx.x;     // 0..127
  float M = MNEG;
#pragma unroll
  for (int c = 0; c < NSLOT; ++c) M = fmaxf(M, mlp[((size_t)p * NSLOT + c) * 2]);
  float L = 0.f, O = 0.f;
#pragma unroll 8
  for (int c = 0; c < NSLOT; ++c) {
    const float mi = mlp[((size_t)p * NSLOT + c) * 2];
    const float w = __expf(mi - M);
    L += w * mlp[((size_t)p * NSLOT + c) * 2 + 1];
    O += w * opart[((size_t)p * NSLOT + c) * HD + d];
  }
  ow[(size_t)p * HD + d] = O / L;
}

// ---------------- sum GEMM partials ----------------
__global__ __launch_bounds__(256)
void sum_partials(const float* __restrict__ part, float* __restrict__ out,
                  const int total4, const int nseg, const int stride) {
  const int i = blockIdx.x * 256 + threadIdx.x;
  if (i >= total4) return;
  float4 s = make_float4(0.f, 0.f, 0.f, 0.f);
  for (int g = 0; g < nseg; ++g) {
    const float4 v = *(const float4*)(part + (size_t)g * stride + (size_t)i * 4);
    s.x += v.x; s.y += v.y; s.z += v.z; s.w += v.w;
  }
  *(float4*)(out + (size_t)i * 4) = s;
}

extern "C" void kernel_launch(void* const* d_in, const int* in_sizes, int n_in,
                              void* d_out, int out_size, void* d_ws, size_t ws_size,
                              hipStream_t stream) {
  const float* x    = (const float*)d_in[0];
  const float* ck   = (const float*)d_in[1];
  const float* cv   = (const float*)d_in[2];
  const float* wqkv = (const float*)d_in[3];
  const float* wo   = (const float*)d_in[4];
  const int*   ctx  = (const int*)d_in[5];

  float* ws    = (float*)d_ws;
  float* pqkv  = ws;                                        // 8*32*6144
  float* qw    = pqkv + (size_t)NSEG * BATCH * QKVN;        // 32*4096
  float* kn    = qw + (size_t)BATCH * DIM;                  // 32*1024
  float* vn    = kn + (size_t)BATCH * NKV * HD;             // 32*1024
  float* opart = vn + (size_t)BATCH * NKV * HD;             // 1024*16*128
  float* mlp   = opart + (size_t)1024 * NSLOT * HD;         // 1024*16*2
  float* ow    = mlp + (size_t)1024 * NSLOT * 2;            // 32*4096
  float* pout  = pqkv;                                      // reuse (dead after qkv_combine)

  gemm_partial<<<dim3(QKVN / GN, NSEG), 256, 0, stream>>>(x, wqkv, pqkv, QKVN);
  qkv_combine<<<dim3(BATCH * QKVN / 2 / 256), 256, 0, stream>>>(pqkv, ctx, qw, kn, vn);
  attn_fd<<<dim3(BATCH * NCHB), 256, 0, stream>>>(qw, kn, vn, ck, cv, ctx, opart, mlp);
  attn_combine<<<dim3(BATCH * NHEAD), HD, 0, stream>>>(opart, mlp, ow);
  gemm_partial<<<dim3(DIM / GN, NSEG), 256, 0, stream>>>(ow, wo, pout, DIM);
  sum_partials<<<dim3((BATCH * DIM / 4 + 255) / 256), 256, 0, stream>>>(
      pout, (float*)d_out, BATCH * DIM / 4, NSEG, BATCH * DIM);
}